// Round 12
// baseline (132.388 us; speedup 1.0000x reference)
//
#include <hip/hip_runtime.h>

#define BATCH  4096
#define NROWS  8192
#define LATENT 2048
#define ZDIM   128
#define PRIORc       0.3f
#define PRIOR_PRIMEc 0.5f

#define NSIMB 512   // 32 stripe-pairs x 16 column-splits; 65 panels/pair
#define NGEMV 2048

typedef __attribute__((ext_vector_type(8))) short bf16x8;  // 8 bf16 = 4 VGPRs
typedef __attribute__((ext_vector_type(4))) float f32x4;   // MFMA C/D

__device__ inline unsigned short f2bf_rne(float f) {
    unsigned int u = __float_as_uint(f);
    u = u + 0x7fffu + ((u >> 16) & 1u);
    return (unsigned short)(u >> 16);
}

__device__ inline float wave_reduce_sum(float v) {
#pragma unroll
    for (int m = 1; m < 64; m <<= 1) v += __shfl_xor(v, m, 64);
    return v;
}

// async global->LDS, 16B per lane (dest = wave-uniform base + lane*16)
__device__ inline void gload_lds16(const void* g, void* l) {
    __builtin_amdgcn_global_load_lds(
        (const __attribute__((address_space(1))) unsigned int*)g,
        (__attribute__((address_space(3))) unsigned int*)l, 16, 0, 0);
}

// ZSCALE = sqrt(2 * log2(e)): folds 1/TEMP + exp->exp2 into the bf16
// fragments so the sim epilogue is one native v_exp per element.
#define ZSCALE 1.69864464f

// ---------------------------------------------------------------------------
// zprep: normalize, scale by ZSCALE, cast bf16, store MFMA-swizzled; exact
// fp32 positive logit; exact bf16 diagonal dexp; zero S_row.
// (R10 note: cooperative single-kernel fusion fails under graph capture —
// keep the multi-kernel structure.)
// ---------------------------------------------------------------------------
__global__ void k_zprep(const float* __restrict__ z_i, const float* __restrict__ z_j,
                        unsigned short* __restrict__ znb, float* __restrict__ pos,
                        float* __restrict__ dexp, float* __restrict__ S_row) {
    int bid = blockIdx.x;
    int wave = threadIdx.x >> 6, lane = threadIdx.x & 63;
    if (threadIdx.x < 8) S_row[bid * 8 + threadIdx.x] = 0.f;
    int r = bid * 4 + wave;               // 0..4095
    int p = r + BATCH;
    float2 a = ((const float2*)(z_i + (size_t)r * ZDIM))[lane];
    float2 c = ((const float2*)(z_j + (size_t)r * ZDIM))[lane];
    float sa = wave_reduce_sum(a.x * a.x + a.y * a.y);
    float sc = wave_reduce_sum(c.x * c.x + c.y * c.y);
    float dd = wave_reduce_sum(a.x * c.x + a.y * c.y);
    float inva = 1.f / fmaxf(sqrtf(sa), 1e-8f);
    float invc = 1.f / fmaxf(sqrtf(sc), 1e-8f);
    if (lane == 0) {
        float pv = 2.0f * dd * inva * invc;   // cos-sim / TEMP, exact fp32
        pos[r] = pv;
        pos[p] = pv;
    }
    int kt = lane >> 4;
    int q  = (lane >> 2) & 3;
    int j  = (lane & 3) * 2;
    int lrow = q * 16;
    float fa = inva * ZSCALE, fc = invc * ZSCALE;
    ushort2 wa; wa.x = f2bf_rne(a.x * fa); wa.y = f2bf_rne(a.y * fa);
    ushort2 wc; wc.x = f2bf_rne(c.x * fc); wc.y = f2bf_rne(c.y * fc);
    {   // row r (from z_i)
        size_t off = ((size_t)((r >> 4) * 4 + kt) * 64 + (lrow + (r & 15))) * 8 + j;
        *(ushort2*)(znb + off) = wa;
    }
    {   // row p (from z_j)
        size_t off = ((size_t)((p >> 4) * 4 + kt) * 64 + (lrow + (p & 15))) * 8 + j;
        *(ushort2*)(znb + off) = wc;
    }
    // diagonal of the bf16 sim matrix, fp32-accumulated like MFMA does
    float ax = __uint_as_float((unsigned)wa.x << 16);
    float ay = __uint_as_float((unsigned)wa.y << 16);
    float cx = __uint_as_float((unsigned)wc.x << 16);
    float cy = __uint_as_float((unsigned)wc.y << 16);
    float da = wave_reduce_sum(ax * ax + ay * ay);
    float dc = wave_reduce_sum(cx * cx + cy * cy);
    if (lane == 0) {
        dexp[r] = __builtin_amdgcn_exp2f(da);
        dexp[p] = __builtin_amdgcn_exp2f(dc);
    }
}

// ---------------------------------------------------------------------------
// Main kernel, PANEL-SWEEP restructure (R12). Six interior theories died
// while k_main sat at ~40us with all pipes <25% busy — the untouched suspect
// is per-tile serial overhead: 2080 single-tile blocks each paying a cold
// B-stage + vmcnt(0) barrier drain (~1000cy, unhidden), an A reload (66MB
// grid-wide), and a 64-shfl epilogue. Now:
//   bids [0,512): sim. Block = stripe-pair (i0, 63-i0) [65 panels, perfectly
//   balanced] x 1-of-16 column split -> 4-5 panels/block, ONE round at
//   2 blocks/CU (64KB LDS). Double-buffered B: stage panel p+1 BEFORE
//   computing panel p (latency hides under MFMA+exp); ONE barrier per panel.
//   A loaded once per stripe (<=2x/block). Row-sums accumulate in REGISTERS
//   across the sweep, flushed by direct global atomics 2x/block (16x fewer
//   epilogues); col-sums per panel via 2 shfl + predicated atomic (skipped
//   on diagonal tiles; diagonal self-sim handled exactly via dexp).
//   bids [512,2560): logit GEMV, backfills sim's tail (R8: fusion ~ +7us).
// __launch_bounds__(256,2): VGPR cap 256 (body ~140), LDS-limited anyway.
// ---------------------------------------------------------------------------
__global__ void __launch_bounds__(256, 2) k_main(
        const unsigned short* __restrict__ znb, float* __restrict__ S_row,
        const float* __restrict__ h_i, const float* __restrict__ h_j,
        const float* __restrict__ W, const float* __restrict__ bb,
        float* __restrict__ logits) {
    int bid = blockIdx.x;
    int lane = threadIdx.x & 63, wave = threadIdx.x >> 6;
    if (bid < NSIMB) {
        int pairIdx = bid >> 4;           // 0..31
        int sub = bid & 15;               // 0..15
        int i0 = pairIdx, i1 = 63 - pairIdx;
        int n0 = 64 - i0;                 // panels in stripe i0 (>=33 > sub)
        int q = lane >> 4, t = lane & 15;
        const bf16x8* zf = (const bf16x8*)znb;

        __shared__ __align__(16) unsigned char bpan[2][32768];

        // prologue: stage first panel (p = sub, always in stripe i0)
        {
            int j0 = i0 + sub;
            const unsigned char* gsrc = (const unsigned char*)znb + (size_t)j0 * 32768;
#pragma unroll
            for (int u = 0; u < 8; ++u)
                gload_lds16(gsrc + u * 4096 + wave * 1024 + lane * 16,
                            bpan[0] + u * 4096 + wave * 1024);
        }

        // A fragments for stripe i0
        int stripe = i0;
        bf16x8 a[4][4];
        {
            int gA = i0 * 8 + (wave >> 1) * 4;
#pragma unroll
            for (int mt = 0; mt < 4; ++mt)
#pragma unroll
                for (int kt = 0; kt < 4; ++kt)
                    a[mt][kt] = zf[(size_t)((gA + mt) * 4 + kt) * 64 + lane];
        }

        float s[16];
#pragma unroll
        for (int idx = 0; idx < 16; ++idx) s[idx] = 0.f;

        __syncthreads();   // drains prologue staging (vmcnt(0))

        int buf = 0;
        for (int p = sub; p < 65; p += 16) {
            int pi = (p < n0) ? i0 : i1;
            int pj = (p < n0) ? (i0 + p) : (i1 + (p - n0));

            // stage NEXT panel into the other buffer (issue earliest; the
            // end-of-iteration barrier drains it before next compute)
            int pn = p + 16;
            if (pn < 65) {
                int nj = (pn < n0) ? (i0 + pn) : (i1 + (pn - n0));
                const unsigned char* gsrc = (const unsigned char*)znb + (size_t)nj * 32768;
#pragma unroll
                for (int u = 0; u < 8; ++u)
                    gload_lds16(gsrc + u * 4096 + wave * 1024 + lane * 16,
                                bpan[buf ^ 1] + u * 4096 + wave * 1024);
            }

            // stripe switch: flush row-sums of old stripe, reload A, zero s
            if (pi != stripe) {
#pragma unroll
                for (int idx = 0; idx < 16; ++idx) {
                    float v = s[idx];
                    v += __shfl_xor(v, 1, 64);
                    v += __shfl_xor(v, 2, 64);
                    v += __shfl_xor(v, 4, 64);
                    v += __shfl_xor(v, 8, 64);
                    if (t == 0)
                        atomicAdd(&S_row[stripe * 128 + (wave >> 1) * 64 +
                                         (idx >> 2) * 16 + q * 4 + (idx & 3)], v);
                }
                stripe = pi;
                int gA = pi * 8 + (wave >> 1) * 4;
#pragma unroll
                for (int mt = 0; mt < 4; ++mt)
#pragma unroll
                    for (int kt = 0; kt < 4; ++kt)
                        a[mt][kt] = zf[(size_t)((gA + mt) * 4 + kt) * 64 + lane];
#pragma unroll
                for (int idx = 0; idx < 16; ++idx) s[idx] = 0.f;
            }

            // compute panel from bpan[buf]
            float c[4];
#pragma unroll
            for (int nt = 0; nt < 4; ++nt) {
                bf16x8 b[4];
#pragma unroll
                for (int kt = 0; kt < 4; ++kt)
                    b[kt] = *(const bf16x8*)(bpan[buf] +
                            ((size_t)(((wave & 1) * 4 + nt) * 4 + kt) * 1024) + lane * 16);
                f32x4 acc[4];
                f32x4 zero = {0.f, 0.f, 0.f, 0.f};
#pragma unroll
                for (int mt = 0; mt < 4; ++mt) acc[mt] = zero;
#pragma unroll
                for (int kt = 0; kt < 4; ++kt)
#pragma unroll
                    for (int mt = 0; mt < 4; ++mt)
                        acc[mt] = __builtin_amdgcn_mfma_f32_16x16x32_bf16(a[mt][kt], b[kt], acc[mt], 0, 0, 0);
                float csum = 0.f;
#pragma unroll
                for (int mt = 0; mt < 4; ++mt)
#pragma unroll
                    for (int reg = 0; reg < 4; ++reg) {
                        float e = __builtin_amdgcn_exp2f(acc[mt][reg]);
                        s[mt * 4 + reg] += e;
                        csum += e;
                    }
                c[nt] = csum;
            }

            // col-sum flush (transpose contribution); skip on diagonal tiles
            if (pi != pj) {
#pragma unroll
                for (int nt = 0; nt < 4; ++nt) {
                    float v = c[nt];
                    v += __shfl_xor(v, 16, 64);
                    v += __shfl_xor(v, 32, 64);
                    if (q == 0)
                        atomicAdd(&S_row[pj * 128 + (wave & 1) * 64 + nt * 16 + t], v);
                }
            }

            __syncthreads();   // all waves done with bpan[buf]; next stage drained
            buf ^= 1;
        }

        // final row-sum flush for the last stripe
#pragma unroll
        for (int idx = 0; idx < 16; ++idx) {
            float v = s[idx];
            v += __shfl_xor(v, 1, 64);
            v += __shfl_xor(v, 2, 64);
            v += __shfl_xor(v, 4, 64);
            v += __shfl_xor(v, 8, 64);
            if (t == 0)
                atomicAdd(&S_row[stripe * 128 + (wave >> 1) * 64 +
                                 (idx >> 2) * 16 + q * 4 + (idx & 3)], v);
        }
    } else {
        int r = (bid - NSIMB) * 4 + wave;     // 0..8191
        const float* h = (r < BATCH) ? (h_i + (size_t)r * LATENT)
                                     : (h_j + (size_t)(r - BATCH) * LATENT);
        const f32x4* h4 = (const f32x4*)h;
        const f32x4* w4 = (const f32x4*)W;
        float s = 0.f;
#pragma unroll
        for (int itr = 0; itr < 8; ++itr) {
            f32x4 av = h4[itr * 64 + lane];
            f32x4 wv = w4[itr * 64 + lane];
            s += av.x * wv.x + av.y * wv.y + av.z * wv.z + av.w * wv.w;
        }
        s = wave_reduce_sum(s);
        if (lane == 0) logits[r] = s + bb[0];
    }
}

// Single block: nnPU risk from logits+target, NT-Xent sum from
// S_row (minus exact diagonal dexp) + pos, weighted combine.
__global__ void k_final(const float* __restrict__ S_row, const float* __restrict__ pos,
                        const float* __restrict__ dexp, const float* __restrict__ logits,
                        const int* __restrict__ target,
                        const float* __restrict__ w_onnpu, float* __restrict__ out) {
    float nt_s = 0.f;
    for (int r = threadIdx.x; r < NROWS; r += 1024)
        nt_s += __logf(S_row[r] - dexp[r]) - pos[r];
    float v[8];
#pragma unroll
    for (int i = 0; i < 8; ++i) v[i] = 0.f;
    for (int r = threadIdx.x; r < BATCH; r += 1024) {
        float li = logits[r], lj = logits[BATCH + r];
        bool p = (target[r] == 1);
        float si_n = 1.f / (1.f + __expf(li));
        float si_p = 1.f / (1.f + __expf(-li));
        float sj_n = 1.f / (1.f + __expf(lj));
        float sj_p = 1.f / (1.f + __expf(-lj));
        v[0] += p ? 1.f : 0.f;
        v[1] += p ? 0.f : 1.f;
        v[2] += p ? si_n : 0.f;
        v[3] += p ? si_p : 0.f;
        v[4] += p ? 0.f : si_p;
        v[5] += p ? sj_n : 0.f;
        v[6] += p ? sj_p : 0.f;
        v[7] += p ? 0.f : sj_p;
    }
    __shared__ float red[16][9];
    int wave = threadIdx.x >> 6, lane = threadIdx.x & 63;
    nt_s = wave_reduce_sum(nt_s);
#pragma unroll
    for (int i = 0; i < 8; ++i) v[i] = wave_reduce_sum(v[i]);
    if (lane == 0) {
        red[wave][0] = nt_s;
#pragma unroll
        for (int i = 0; i < 8; ++i) red[wave][1 + i] = v[i];
    }
    __syncthreads();
    if (threadIdx.x == 0) {
        float t[9];
#pragma unroll
        for (int i = 0; i < 9; ++i) {
            float acc = 0.f;
#pragma unroll
            for (int wv = 0; wv < 16; ++wv) acc += red[wv][i];
            t[i] = acc;
        }
        float ntxent = t[0] / (float)NROWS;
        float np = fmaxf(1.f, t[1]), nu = fmaxf(1.f, t[2]);
        float pr_i = PRIOR_PRIMEc / np * t[3];
        float nr_i = (1.f - PRIOR_PRIMEc) / (nu * (1.f - PRIORc)) * t[5]
                   - (1.f - PRIOR_PRIMEc) * PRIORc / (np * (1.f - PRIORc)) * t[4];
        float li_loss = (nr_i < 0.f) ? -nr_i : (pr_i + nr_i);
        float pr_j = PRIOR_PRIMEc / np * t[6];
        float nr_j = (1.f - PRIOR_PRIMEc) / (nu * (1.f - PRIORc)) * t[8]
                   - (1.f - PRIOR_PRIMEc) * PRIORc / (np * (1.f - PRIORc)) * t[7];
        float lj_loss = (nr_j < 0.f) ? -nr_j : (pr_j + nr_j);
        float onnpu = 0.5f * (li_loss + lj_loss);
        float w = w_onnpu[0];
        out[0] = w * onnpu + (1.f - w) * ntxent;
    }
}

extern "C" void kernel_launch(void* const* d_in, const int* in_sizes, int n_in,
                              void* d_out, int out_size, void* d_ws, size_t ws_size,
                              hipStream_t stream) {
    const float* h_i = (const float*)d_in[0];
    const float* h_j = (const float*)d_in[1];
    const float* z_i = (const float*)d_in[2];
    const float* z_j = (const float*)d_in[3];
    const int* target = (const int*)d_in[4];
    const float* W = (const float*)d_in[5];
    const float* b = (const float*)d_in[6];
    const float* w_onnpu = (const float*)d_in[7];

    char* ws = (char*)d_ws;
    unsigned short* znb = (unsigned short*)ws;              // 2 MB swizzled bf16
    float* S_row  = (float*)(ws + 2097152);                 // 32 KB
    float* pos    = (float*)(ws + 2097152 + 32768);         // 32 KB
    float* logits = (float*)(ws + 2097152 + 65536);         // 32 KB
    float* dexp   = (float*)(ws + 2097152 + 98304);         // 32 KB
    float* out = (float*)d_out;

    k_zprep<<<1024, 256, 0, stream>>>(z_i, z_j, znb, pos, dexp, S_row);
    k_main<<<NSIMB + NGEMV, 256, 0, stream>>>(znb, S_row, h_i, h_j, W, b, logits);
    k_final<<<1, 1024, 0, stream>>>(S_row, pos, dexp, logits, target, w_onnpu, out);
}